// Round 5
// baseline (158.880 us; speedup 1.0000x reference)
//
#include <hip/hip_runtime.h>
#include <stdint.h>

// Problem constants (fixed by reference setup_inputs)
#define NPOS 512   // N
#define NH   64    // H
#define NM   1024  // M
#define NB   256   // B
#define NM1  511   // N-1

typedef __attribute__((ext_vector_type(8)))  short bf16x8;
typedef __attribute__((ext_vector_type(16))) float f32x16;
typedef __attribute__((ext_vector_type(4)))  float f32x4;
typedef __attribute__((ext_vector_type(4)))  int   i32x4;

#if __has_builtin(__builtin_amdgcn_exp2f)
#define EXP2F(x) __builtin_amdgcn_exp2f(x)
#else
#define EXP2F(x) __expf((x) * 0.69314718055994531f)
#endif

__device__ __forceinline__ unsigned short f2bf(float x) {
    unsigned u = __float_as_uint(x);
    u = (u + 0x7FFFu + ((u >> 16) & 1u)) >> 16;   // RNE
    return (unsigned short)u;
}
__device__ __forceinline__ int pack2(unsigned short a, unsigned short b) {
    return (int)a | ((int)b << 16);
}

// =====================================================================
// ============ PATH A (large workspace): E-precompute design ==========
// =====================================================================

// ---------------- kAE: fused prep = {k0 seq->bf16 + zero out, k1a BnT softmax,
//   k1c plusT transpose, kE masked-exp of A -> bf16 E + f32 Z}. 783 blocks. ---
__global__ __launch_bounds__(256, 4)
void kAE_prep(const float* __restrict__ seq, const float* __restrict__ Bl,
              const float* __restrict__ mem, const float* __restrict__ Al,
              unsigned short* __restrict__ seq_bf, float* __restrict__ BnT,
              float* __restrict__ plusT, unsigned short* __restrict__ Ew,
              float* __restrict__ Zb, float* __restrict__ out) {
    const int bid = blockIdx.x, t = threadIdx.x;
    if (bid < 128) {
        // --- k0: sequences fp32 -> bf16 (exact for +/-1) ---
        if (bid == 0 && t == 0) out[0] = 0.f;
        int idx = (bid * 256 + t) * 4;
        f32x4 v = *(const f32x4*)(seq + idx);
        int2 o;
        o.x = pack2(f2bf(v.x), f2bf(v.y));
        o.y = pack2(f2bf(v.z), f2bf(v.w));
        *(int2*)(seq_bf + idx) = o;
    } else if (bid < 144) {
        // --- k1a: Bn = softmax(B_logits, axis=-1), stored transposed ---
        const int h = (bid - 128) * 4 + (t >> 6), l = t & 63;
        float v[8]; float mx = -1e30f;
#pragma unroll
        for (int j = 0; j < 8; j++) { v[j] = Bl[h * NPOS + l + 64 * j]; mx = fmaxf(mx, v[j]); }
#pragma unroll
        for (int o = 32; o; o >>= 1) mx = fmaxf(mx, __shfl_xor(mx, o));
        float s = 0.f;
#pragma unroll
        for (int j = 0; j < 8; j++) { v[j] = __expf(v[j] - mx); s += v[j]; }
#pragma unroll
        for (int o = 32; o; o >>= 1) s += __shfl_xor(s, o);
        float r = 1.0f / s;
#pragma unroll
        for (int j = 0; j < 8; j++) BnT[(l + 64 * j) * NH + h] = v[j] * r;
    } else if (bid < 272) {
        // --- k1c: plusT[n][m] via LDS 64x64 tile transpose ---
        __shared__ float sT[64][65];
        const int bb = bid - 144;
        const int mt = bb >> 3, nt = bb & 7;
        const int rr = t >> 2, cc = t & 3;
        const float* src = mem + (size_t)(mt * 64 + rr) * NPOS + nt * 64 + cc * 16;
#pragma unroll
        for (int j = 0; j < 4; j++) {
            f32x4 v = *(const f32x4*)(src + j * 4);
            sT[rr][cc * 16 + j * 4 + 0] = (v.x > 0.f) ? 1.f : 0.f;
            sT[rr][cc * 16 + j * 4 + 1] = (v.y > 0.f) ? 1.f : 0.f;
            sT[rr][cc * 16 + j * 4 + 2] = (v.z > 0.f) ? 1.f : 0.f;
            sT[rr][cc * 16 + j * 4 + 3] = (v.w > 0.f) ? 1.f : 0.f;
        }
        __syncthreads();
        float* dst = plusT + (size_t)(nt * 64 + rr) * NM + mt * 64 + cc * 16;
#pragma unroll
        for (int j = 0; j < 4; j++) {
            f32x4 o;
            o.x = sT[cc * 16 + j * 4 + 0][rr];
            o.y = sT[cc * 16 + j * 4 + 1][rr];
            o.z = sT[cc * 16 + j * 4 + 2][rr];
            o.w = sT[cc * 16 + j * 4 + 3][rr];
            *(f32x4*)(dst + j * 4) = o;
        }
    } else {
        // --- kE: E[n][kk][h][i] = bf16(exp(A[n,h,kk*64+i])) masked i<n;
        //         Z[n-1][h] = f32 row sum. One block per n (1..511). ---
        const int n = bid - 271;                    // 1..511
        const int h = t >> 2, j = t & 3;
        const int lim = ((n + 63) >> 6) * 64;       // full slabs written
        const float* Ar = Al + ((size_t)n * NH + h) * NPOS;
        unsigned short* Er = Ew + (size_t)(n - 1) * 32768 + h * 64;
        float zp = 0.f;
#pragma unroll 4
        for (int g = 0; g < 16; g++) {
            const int i0 = g * 32 + j * 8;          // this thread's 8 elems in block g
            if (g * 32 >= lim) break;               // uniform over j (lim mult of 64)
            f32x4 v0 = *(const f32x4*)(Ar + i0);
            f32x4 v1 = *(const f32x4*)(Ar + i0 + 4);
            float e0 = (i0 + 0 < n) ? __expf(v0.x) : 0.f;
            float e1 = (i0 + 1 < n) ? __expf(v0.y) : 0.f;
            float e2 = (i0 + 2 < n) ? __expf(v0.z) : 0.f;
            float e3 = (i0 + 3 < n) ? __expf(v0.w) : 0.f;
            float e4 = (i0 + 4 < n) ? __expf(v1.x) : 0.f;
            float e5 = (i0 + 5 < n) ? __expf(v1.y) : 0.f;
            float e6 = (i0 + 6 < n) ? __expf(v1.z) : 0.f;
            float e7 = (i0 + 7 < n) ? __expf(v1.w) : 0.f;
            zp += ((e0 + e1) + (e2 + e3)) + ((e4 + e5) + (e6 + e7));
            i32x4 w;
            w.x = pack2(f2bf(e0), f2bf(e1));
            w.y = pack2(f2bf(e2), f2bf(e3));
            w.z = pack2(f2bf(e4), f2bf(e5));
            w.w = pack2(f2bf(e6), f2bf(e7));
            *(i32x4*)(Er + (i0 >> 6) * 4096 + (i0 & 63)) = w;
        }
        zp += __shfl_xor(zp, 1);
        zp += __shfl_xor(zp, 2);
        if (j == 0) Zb[(n - 1) * 64 + h] = zp;
    }
}

// ------------- phase-2 helpers (static indexing only; rule #20) --------------
__device__ __forceinline__ void p2_load(bf16x8 (&p)[4], const unsigned short* __restrict__ phimu,
                                        int tile, int r, int half) {
#pragma unroll
    for (int kq = 0; kq < 4; kq++)
        p[kq] = *(const bf16x8*)(phimu + (size_t)(tile * 32 + r) * NH + kq * 16 + half * 8);
}
// first MFMA consumes a persistent zeroed C (no per-tile accumulator init)
__device__ __forceinline__ void p2_mfma(const bf16x8 (&p)[4], const bf16x8 (&q0)[4], const bf16x8 (&q1)[4],
                                        const f32x16& z, f32x16& a0, f32x16& a1) {
    a0 = __builtin_amdgcn_mfma_f32_32x32x16_bf16(p[0], q0[0], z, 0, 0, 0);
    a1 = __builtin_amdgcn_mfma_f32_32x32x16_bf16(p[0], q1[0], z, 0, 0, 0);
#pragma unroll
    for (int kq = 1; kq < 4; kq++) {
        a0 = __builtin_amdgcn_mfma_f32_32x32x16_bf16(p[kq], q0[kq], a0, 0, 0, 0);
        a1 = __builtin_amdgcn_mfma_f32_32x32x16_bf16(p[kq], q1[kq], a1, 0, 0, 0);
    }
}
__device__ __forceinline__ void p2_expsum(const f32x16& a0, const f32x16& a1, const float* s_plus,
                                          int mb, int half,
                                          f32x4& den0, f32x4& num0, f32x4& den1, f32x4& num1) {
#pragma unroll
    for (int g = 0; g < 4; g++) {
        f32x4 pv = *(const f32x4*)(s_plus + mb + 4 * half + 8 * g);
        f32x4 e0, e1;
#pragma unroll
        for (int j = 0; j < 4; j++) {
            e0[j] = EXP2F(a0[4 * g + j]);   // m = mb + j + 8*g + 4*half
            e1[j] = EXP2F(a1[4 * g + j]);
        }
        den0 += e0; num0 += e0 * pv;
        den1 += e1; num1 += e1 * pv;
    }
}

// ---------------- k23E: consumes precomputed bf16 E + f32 Z ------------------
// grid 511, 256 thr = 4 waves. Pairing remap (even->big n, odd->small n).
__global__ __launch_bounds__(256, 2)
void k23_fusedE(const unsigned short* __restrict__ Ew, const float* __restrict__ Zb,
                const unsigned short* __restrict__ seq_bf,
                const unsigned short* __restrict__ phimu, const float* __restrict__ plusT,
                const float* __restrict__ seq, float* __restrict__ out) {
    __shared__ __align__(16) unsigned short e_lds[2][64 * 72];   // E double buffer
    __shared__ __align__(16) unsigned short q_lds[256 * 72];     // q tile (36864 B)
    __shared__ float s_plus[NM];
    __shared__ float w_lds[4];                                   // wave BCE partials

    const int t = threadIdx.x;
    const int c = blockIdx.x >> 1;
    const int n = (blockIdx.x & 1) ? (1 + c) : (NM1 - c);        // pairing remap
    const int ksteps = (n + 63) >> 6;
    const int wv = t >> 6, lane = t & 63, half = lane >> 5, r = lane & 31;

    // stage plus row + Z early (Z ready since launch 1)
    *(f32x4*)(s_plus + t * 4) = *(const f32x4*)(plusT + (size_t)n * NM + t * 4);
    const float Zr0 = Zb[(n - 1) * 64 + r];
    const float Zr1 = Zb[(n - 1) * 64 + 32 + r];

    // ================= phase 1: hat_phi tile (256 b x 64 h) =================
    const unsigned short* Eb = Ew + (size_t)(n - 1) * 32768;
    const int eh = t >> 2, ec = (t & 3) * 16;                    // E staging map
    const unsigned short* s0 = seq_bf + (size_t)(wv * 64 + r) * NPOS;
    const unsigned short* s1 = seq_bf + (size_t)(wv * 64 + 32 + r) * NPOS;

    f32x16 acc00, acc01, acc10, acc11;
#pragma unroll
    for (int i = 0; i < 16; i++) { acc00[i] = 0.f; acc01[i] = 0.f; acc10[i] = 0.f; acc11[i] = 0.f; }

    bf16x8 er0, er1, sc0[4], sc1[4], sn0[4], sn1[4];
    er0 = *(const bf16x8*)(Eb + eh * 64 + ec);
    er1 = *(const bf16x8*)(Eb + eh * 64 + ec + 8);
#pragma unroll
    for (int kq = 0; kq < 4; kq++) {
        sc0[kq] = *(const bf16x8*)(s0 + kq * 16 + half * 8);
        sc1[kq] = *(const bf16x8*)(s1 + kq * 16 + half * 8);
    }

    for (int kk = 0; kk < ksteps; kk++) {
        // 1. stage E tile from regs into current buffer
        {
            unsigned short* ep = (unsigned short*)e_lds[kk & 1] + eh * 72 + ec;
            *(bf16x8*)(ep)     = er0;
            *(bf16x8*)(ep + 8) = er1;
        }
        // 2. prefetch k+1 (E slab + S frags) — stays in flight across barrier
        if (kk + 1 < ksteps) {
            const unsigned short* nb = Eb + (kk + 1) * 4096 + eh * 64 + ec;
            er0 = *(const bf16x8*)(nb);
            er1 = *(const bf16x8*)(nb + 8);
            const int k0 = (kk + 1) * 64;
#pragma unroll
            for (int kq = 0; kq < 4; kq++) {
                sn0[kq] = *(const bf16x8*)(s0 + k0 + kq * 16 + half * 8);
                sn1[kq] = *(const bf16x8*)(s1 + k0 + kq * 16 + half * 8);
            }
        }
        // 3. LDS-only fence + raw barrier (global prefetches NOT drained)
        asm volatile("s_waitcnt lgkmcnt(0)" ::: "memory");
        __builtin_amdgcn_s_barrier();
        asm volatile("" ::: "memory");
        // 4. MFMA: D[b][h] += S[b,i] * E[h,i]
        {
            const unsigned short* sB0 = (const unsigned short*)e_lds[kk & 1] + r * 72;
            const unsigned short* sB1 = sB0 + 32 * 72;
#pragma unroll
            for (int kq = 0; kq < 4; kq++) {
                const int ko = kq * 16 + half * 8;
                bf16x8 B0 = *(const bf16x8*)(sB0 + ko);
                bf16x8 B1 = *(const bf16x8*)(sB1 + ko);
                acc00 = __builtin_amdgcn_mfma_f32_32x32x16_bf16(sc0[kq], B0, acc00, 0, 0, 0);
                acc01 = __builtin_amdgcn_mfma_f32_32x32x16_bf16(sc0[kq], B1, acc01, 0, 0, 0);
                acc10 = __builtin_amdgcn_mfma_f32_32x32x16_bf16(sc1[kq], B0, acc10, 0, 0, 0);
                acc11 = __builtin_amdgcn_mfma_f32_32x32x16_bf16(sc1[kq], B1, acc11, 0, 0, 0);
            }
        }
        // 5. rotate S fragments
        if (kk + 1 < ksteps) {
#pragma unroll
            for (int kq = 0; kq < 4; kq++) { sc0[kq] = sn0[kq]; sc1[kq] = sn1[kq]; }
        }
    }
    // epilogue: scale by 1/Z[h], write q tile into q_lds (wave-own rows).
    {
        float rz0 = 1.0f / Zr0;
        float rz1 = 1.0f / Zr1;
#pragma unroll
        for (int reg = 0; reg < 16; reg++) {
            int row = (reg & 3) + 8 * (reg >> 2) + 4 * half;
            q_lds[(wv * 64 + row) * 72 + r]            = f2bf(acc00[reg] * rz0);
            q_lds[(wv * 64 + row) * 72 + 32 + r]       = f2bf(acc01[reg] * rz1);
            q_lds[(wv * 64 + 32 + row) * 72 + r]       = f2bf(acc10[reg] * rz0);
            q_lds[(wv * 64 + 32 + row) * 72 + 32 + r]  = f2bf(acc11[reg] * rz1);
        }
    }

    // ================= phase 2: retrieval softmax =================
    bf16x8 p[4], pn[4];
    p2_load(p, phimu, 0, r, half);             // global loads issue first
    bf16x8 q0[4], q1[4];
#pragma unroll
    for (int kq = 0; kq < 4; kq++) {
        q0[kq] = *(const bf16x8*)(q_lds + (wv * 64 + r) * 72 + kq * 16 + half * 8);
        q1[kq] = *(const bf16x8*)(q_lds + (wv * 64 + 32 + r) * 72 + kq * 16 + half * 8);
    }
    f32x16 zacc;
#pragma unroll
    for (int i = 0; i < 16; i++) zacc[i] = 0.f;

    f32x4 den0 = {0.f,0.f,0.f,0.f}, num0 = {0.f,0.f,0.f,0.f};
    f32x4 den1 = {0.f,0.f,0.f,0.f}, num1 = {0.f,0.f,0.f,0.f};
    f32x16 a0, a1;

    for (int it = 0; it < 32; ++it) {
        if (it < 31) p2_load(pn, phimu, it + 1, r, half);   // prefetch, no barrier
        p2_mfma(p, q0, q1, zacc, a0, a1);
        p2_expsum(a0, a1, s_plus, it * 32, half, den0, num0, den1, num1);
        if (it < 31) {
#pragma unroll
            for (int kq = 0; kq < 4; kq++) p[kq] = pn[kq];
        }
    }

    float d0 = (den0[0] + den0[1]) + (den0[2] + den0[3]);
    float nu0 = (num0[0] + num0[1]) + (num0[2] + num0[3]);
    float d1 = (den1[0] + den1[1]) + (den1[2] + den1[3]);
    float nu1 = (num1[0] + num1[1]) + (num1[2] + num1[3]);
    d0 += __shfl_xor(d0, 32); nu0 += __shfl_xor(nu0, 32);
    d1 += __shfl_xor(d1, 32); nu1 += __shfl_xor(nu1, 32);

    float* dsum = (float*)e_lds;          // 512 floats (e_lds dead after phase 1)
    float* nsum = dsum + 256;
    if (half == 0) {
        dsum[wv * 64 + r]      = d0; nsum[wv * 64 + r]      = nu0;
        dsum[wv * 64 + 32 + r] = d1; nsum[wv * 64 + 32 + r] = nu1;
    }
    __syncthreads();
    {
        float dd = dsum[t], nn = nsum[t];
        float p2 = nn / dd;
        p2 = fminf(fmaxf(p2, 1e-6f), 1.0f - 1e-6f);
        float tg = seq[(size_t)t * NPOS + n];
        float bce = (tg > 0.f) ? -logf(p2) : -logf(1.0f - p2);
#pragma unroll
        for (int o = 32; o; o >>= 1) bce += __shfl_xor(bce, o);
        if (lane == 0) w_lds[wv] = bce;
    }
    __syncthreads();
    if (t == 0)
        atomicAdd(out, (w_lds[0] + w_lds[1] + w_lds[2] + w_lds[3]) * (1.0f / 130816.0f));
}

// =====================================================================
// ====== PATH B (small workspace): round-0 kernels, verbatim ==========
// ====== (best measured: k23 = 56.4 us, total = 145.6 us)    ==========
// =====================================================================

__global__ __launch_bounds__(256, 4)
void kA_prep(const float* __restrict__ seq, const float* __restrict__ Bl,
             const float* __restrict__ mem,
             unsigned short* __restrict__ seq_bf, float* __restrict__ BnT,
             float* __restrict__ plusT, float* __restrict__ out) {
    const int bid = blockIdx.x, t = threadIdx.x;
    if (bid < 128) {
        if (bid == 0 && t == 0) out[0] = 0.f;
        int idx = (bid * 256 + t) * 4;
        f32x4 v = *(const f32x4*)(seq + idx);
        int2 o;
        o.x = pack2(f2bf(v.x), f2bf(v.y));
        o.y = pack2(f2bf(v.z), f2bf(v.w));
        *(int2*)(seq_bf + idx) = o;
    } else if (bid < 144) {
        const int h = (bid - 128) * 4 + (t >> 6), l = t & 63;
        float v[8]; float mx = -1e30f;
#pragma unroll
        for (int j = 0; j < 8; j++) { v[j] = Bl[h * NPOS + l + 64 * j]; mx = fmaxf(mx, v[j]); }
#pragma unroll
        for (int o = 32; o; o >>= 1) mx = fmaxf(mx, __shfl_xor(mx, o));
        float s = 0.f;
#pragma unroll
        for (int j = 0; j < 8; j++) { v[j] = __expf(v[j] - mx); s += v[j]; }
#pragma unroll
        for (int o = 32; o; o >>= 1) s += __shfl_xor(s, o);
        float r = 1.0f / s;
#pragma unroll
        for (int j = 0; j < 8; j++) BnT[(l + 64 * j) * NH + h] = v[j] * r;
    } else {
        __shared__ float sT[64][65];
        const int bb = bid - 144;
        const int mt = bb >> 3, nt = bb & 7;
        const int rr = t >> 2, cc = t & 3;
        const float* src = mem + (size_t)(mt * 64 + rr) * NPOS + nt * 64 + cc * 16;
#pragma unroll
        for (int j = 0; j < 4; j++) {
            f32x4 v = *(const f32x4*)(src + j * 4);
            sT[rr][cc * 16 + j * 4 + 0] = (v.x > 0.f) ? 1.f : 0.f;
            sT[rr][cc * 16 + j * 4 + 1] = (v.y > 0.f) ? 1.f : 0.f;
            sT[rr][cc * 16 + j * 4 + 2] = (v.z > 0.f) ? 1.f : 0.f;
            sT[rr][cc * 16 + j * 4 + 3] = (v.w > 0.f) ? 1.f : 0.f;
        }
        __syncthreads();
        float* dst = plusT + (size_t)(nt * 64 + rr) * NM + mt * 64 + cc * 16;
#pragma unroll
        for (int j = 0; j < 4; j++) {
            f32x4 o;
            o.x = sT[cc * 16 + j * 4 + 0][rr];
            o.y = sT[cc * 16 + j * 4 + 1][rr];
            o.z = sT[cc * 16 + j * 4 + 2][rr];
            o.w = sT[cc * 16 + j * 4 + 3][rr];
            *(f32x4*)(dst + j * 4) = o;
        }
    }
}

__global__ __launch_bounds__(256, 2)
void k23_fused0(const float* __restrict__ Al, const unsigned short* __restrict__ seq_bf,
                const unsigned short* __restrict__ phimu, const float* __restrict__ plusT,
                const float* __restrict__ seq, float* __restrict__ out) {
    __shared__ __align__(16) unsigned short s_lds[256 * 72];
    __shared__ __align__(16) unsigned short e_lds[64 * 72];
    __shared__ float z_lds[64];
    __shared__ float s_plus[NM];

    const int t = threadIdx.x;
    const int n = NM1 - (int)blockIdx.x;
    const int ksteps = (n + 63) >> 6;
    const int wv = t >> 6, lane = t & 63, half = lane >> 5, r = lane & 31;

    if (t < 64) z_lds[t] = 0.f;
    *(f32x4*)(s_plus + t * 4) = *(const f32x4*)(plusT + n * NM + t * 4);

    const int eh = t >> 2, ei = (t & 3) * 16;
    const float* arow = Al + ((size_t)n * NH + eh) * NPOS + ei;
    const unsigned short* srcS = seq_bf + (size_t)t * NPOS;

    f32x16 acc00, acc01, acc10, acc11;
#pragma unroll
    for (int i = 0; i < 16; i++) { acc00[i] = 0.f; acc01[i] = 0.f; acc10[i] = 0.f; acc11[i] = 0.f; }

    f32x4 ea[4]; i32x4 sa[8];
#pragma unroll
    for (int g = 0; g < 4; g++) ea[g] = *(const f32x4*)(arow + g * 4);
#pragma unroll
    for (int c = 0; c < 8; c++) sa[c] = *(const i32x4*)(srcS + c * 8);
    __syncthreads();

    for (int kk = 0; kk < ksteps; kk++) {
        const int k0 = kk * 64;
        {
            float zp = 0.f;
            unsigned short* ep = e_lds + eh * 72 + ei;
#pragma unroll
            for (int g = 0; g < 4; g++) {
                int i0 = k0 + ei + g * 4;
                float e0 = (i0 + 0 < n) ? __expf(ea[g].x) : 0.f;
                float e1 = (i0 + 1 < n) ? __expf(ea[g].y) : 0.f;
                float e2 = (i0 + 2 < n) ? __expf(ea[g].z) : 0.f;
                float e3 = (i0 + 3 < n) ? __expf(ea[g].w) : 0.f;
                zp += (e0 + e1) + (e2 + e3);
                int2 o; o.x = pack2(f2bf(e0), f2bf(e1)); o.y = pack2(f2bf(e2), f2bf(e3));
                *(int2*)(ep + g * 4) = o;
            }
            zp += __shfl_xor(zp, 1);
            zp += __shfl_xor(zp, 2);
            if ((t & 3) == 0) z_lds[eh] += zp;
        }
        {
            unsigned short* dp = s_lds + t * 72;
#pragma unroll
            for (int c = 0; c < 8; c++) *(i32x4*)(dp + c * 8) = sa[c];
        }
        __syncthreads();
        if (kk + 1 < ksteps) {
#pragma unroll
            for (int g = 0; g < 4; g++) ea[g] = *(const f32x4*)(arow + k0 + 64 + g * 4);
#pragma unroll
            for (int c = 0; c < 8; c++) sa[c] = *(const i32x4*)(srcS + k0 + 64 + c * 8);
        }
        {
            const unsigned short* sA0 = s_lds + (wv * 64 + r) * 72;
            const unsigned short* sA1 = sA0 + 32 * 72;
            const unsigned short* sB0 = e_lds + r * 72;
            const unsigned short* sB1 = sB0 + 32 * 72;
#pragma unroll
            for (int kq = 0; kq < 4; kq++) {
                const int ko = kq * 16 + half * 8;
                bf16x8 A0 = *(const bf16x8*)(sA0 + ko);
                bf16x8 A1 = *(const bf16x8*)(sA1 + ko);
                bf16x8 B0 = *(const bf16x8*)(sB0 + ko);
                bf16x8 B1 = *(const bf16x8*)(sB1 + ko);
                acc00 = __builtin_amdgcn_mfma_f32_32x32x16_bf16(A0, B0, acc00, 0, 0, 0);
                acc01 = __builtin_amdgcn_mfma_f32_32x32x16_bf16(A0, B1, acc01, 0, 0, 0);
                acc10 = __builtin_amdgcn_mfma_f32_32x32x16_bf16(A1, B0, acc10, 0, 0, 0);
                acc11 = __builtin_amdgcn_mfma_f32_32x32x16_bf16(A1, B1, acc11, 0, 0, 0);
            }
        }
        __syncthreads();
    }
    {
        float rz0 = 1.0f / z_lds[r];
        float rz1 = 1.0f / z_lds[32 + r];
#pragma unroll
        for (int reg = 0; reg < 16; reg++) {
            int row = (reg & 3) + 8 * (reg >> 2) + 4 * half;
            s_lds[(wv * 64 + row) * 72 + r]            = f2bf(acc00[reg] * rz0);
            s_lds[(wv * 64 + row) * 72 + 32 + r]       = f2bf(acc01[reg] * rz1);
            s_lds[(wv * 64 + 32 + row) * 72 + r]       = f2bf(acc10[reg] * rz0);
            s_lds[(wv * 64 + 32 + row) * 72 + 32 + r]  = f2bf(acc11[reg] * rz1);
        }
    }
    __syncthreads();

    bf16x8 p[4];
#pragma unroll
    for (int kq = 0; kq < 4; kq++)
        p[kq] = *(const bf16x8*)(phimu + (r) * NH + kq * 16 + half * 8);
    bf16x8 q[2][4];
#pragma unroll
    for (int bs = 0; bs < 2; bs++)
#pragma unroll
        for (int kq = 0; kq < 4; kq++)
            q[bs][kq] = *(const bf16x8*)(s_lds + (wv * 64 + bs * 32 + r) * 72 + kq * 16 + half * 8);

    f32x4 den0 = {0.f,0.f,0.f,0.f}, num0 = {0.f,0.f,0.f,0.f};
    f32x4 den1 = {0.f,0.f,0.f,0.f}, num1 = {0.f,0.f,0.f,0.f};

    for (int it = 0; it < 32; ++it) {
        bf16x8 pn[4];
        if (it < 31) {
#pragma unroll
            for (int kq = 0; kq < 4; kq++)
                pn[kq] = *(const bf16x8*)(phimu + ((it + 1) * 32 + r) * NH + kq * 16 + half * 8);
        }
        f32x16 a0, a1;
#pragma unroll
        for (int i = 0; i < 16; i++) { a0[i] = 0.f; a1[i] = 0.f; }
#pragma unroll
        for (int kq = 0; kq < 4; kq++) {
            a0 = __builtin_amdgcn_mfma_f32_32x32x16_bf16(p[kq], q[0][kq], a0, 0, 0, 0);
            a1 = __builtin_amdgcn_mfma_f32_32x32x16_bf16(p[kq], q[1][kq], a1, 0, 0, 0);
        }
        const int mb = it * 32;
        f32x4 pv[4];
#pragma unroll
        for (int g = 0; g < 4; g++) pv[g] = *(const f32x4*)(s_plus + mb + 4 * half + 8 * g);
#pragma unroll
        for (int g = 0; g < 4; g++) {
            f32x4 e0, e1;
#pragma unroll
            for (int j = 0; j < 4; j++) {
                e0[j] = EXP2F(a0[4 * g + j]);
                e1[j] = EXP2F(a1[4 * g + j]);
            }
            den0 += e0; num0 += e0 * pv[g];
            den1 += e1; num1 += e1 * pv[g];
        }
        if (it < 31) {
#pragma unroll
            for (int kq = 0; kq < 4; kq++) p[kq] = pn[kq];
        }
    }
    float d0 = (den0[0] + den0[1]) + (den0[2] + den0[3]);
    float nu0 = (num0[0] + num0[1]) + (num0[2] + num0[3]);
    float d1 = (den1[0] + den1[1]) + (den1[2] + den1[3]);
    float nu1 = (num1[0] + num1[1]) + (num1[2] + num1[3]);
    d0 += __shfl_xor(d0, 32); nu0 += __shfl_xor(nu0, 32);
    d1 += __shfl_xor(d1, 32); nu1 += __shfl_xor(nu1, 32);

    float* dsum = (float*)e_lds;
    float* nsum = dsum + 256;
    if (half == 0) {
        dsum[wv * 64 + r]      = d0; nsum[wv * 64 + r]      = nu0;
        dsum[wv * 64 + 32 + r] = d1; nsum[wv * 64 + 32 + r] = nu1;
    }
    __syncthreads();
    {
        float dd = dsum[t], nn = nsum[t];
        float p2 = nn / dd;
        p2 = fminf(fmaxf(p2, 1e-6f), 1.0f - 1e-6f);
        float tg = seq[(size_t)t * NPOS + n];
        float bce = (tg > 0.f) ? -logf(p2) : -logf(1.0f - p2);
#pragma unroll
        for (int o = 32; o; o >>= 1) bce += __shfl_xor(bce, o);
        if (lane == 0) z_lds[wv] = bce;
    }
    __syncthreads();
    if (t == 0)
        atomicAdd(out, (z_lds[0] + z_lds[1] + z_lds[2] + z_lds[3]) * (1.0f / 130816.0f));
}

// ---------------- k1b: phi_mu[m,h] = sum_n Bn[h,n]*memory[m,n] -> bf16 -------
// (shared by both paths) PRE-SCALED by log2(e).
__global__ __launch_bounds__(256, 4)
void k1b_phimu(const float* __restrict__ BnT, const float* __restrict__ mem,
               unsigned short* __restrict__ phimu) {
    const int m0 = blockIdx.x * 2, t = threadIdx.x;
    __shared__ float mrow[2][NPOS];
    __shared__ float part[2][256];
    {
        int row = t >> 7, c = (t & 127) * 4;
        *(f32x4*)(&mrow[row][c]) = *(const f32x4*)(mem + (size_t)(m0 + row) * NPOS + c);
    }
    __syncthreads();
    const int h = t & 63, seg = t >> 6;
    float a[2] = {0.f, 0.f};
    float b2[2] = {0.f, 0.f};
    const float* bp = BnT + seg * 128 * NH + h;
#pragma unroll 8
    for (int nn = 0; nn < 128; nn += 2) {
        float x0 = bp[nn * NH], x1 = bp[(nn + 1) * NH];
#pragma unroll
        for (int row = 0; row < 2; row++) {
            a[row]  = fmaf(x0, mrow[row][seg * 128 + nn], a[row]);
            b2[row] = fmaf(x1, mrow[row][seg * 128 + nn + 1], b2[row]);
        }
    }
#pragma unroll
    for (int row = 0; row < 2; row++) part[row][t] = a[row] + b2[row];
    __syncthreads();
    if (t < 64) {
#pragma unroll
        for (int row = 0; row < 2; row++) {
            float s = (part[row][t] + part[row][t + 64]) + (part[row][t + 128] + part[row][t + 192]);
            phimu[(m0 + row) * NH + t] = f2bf(s * 1.4426950408889634f);  // * log2(e)
        }
    }
}

extern "C" void kernel_launch(void* const* d_in, const int* in_sizes, int n_in,
                              void* d_out, int out_size, void* d_ws, size_t ws_size,
                              hipStream_t stream) {
    const float* seq = (const float*)d_in[0];  // (B,N)
    const float* mem = (const float*)d_in[1];  // (M,N)
    const float* Al  = (const float*)d_in[2];  // (N,H,N)
    const float* Bl  = (const float*)d_in[3];  // (H,N)

    char* ws = (char*)d_ws;
    unsigned short* seq_bf = (unsigned short*)(ws + 0);          // 256 KB
    float*          BnT    = (float*)(ws + 262144);              // 128 KB (N,H)
    unsigned short* phimu  = (unsigned short*)(ws + 393216);     // 128 KB (M,H) *log2e
    float*          plusT  = (float*)(ws + 524288);              // 2 MB (N,M)
    float*          Zb     = (float*)(ws + 2621440);             // 128 KB (N-1,H) f32 row sums
    unsigned short* Ew     = (unsigned short*)(ws + 2752512);    // 33.5 MB (N-1)x[8][64][64] bf16
    float*          outp   = (float*)d_out;

    // Ew end = 2752512 + 511*32768*2 = 36,241,408 bytes.
    const size_t WS_NEEDED_E = 2752512 + (size_t)NM1 * 32768 * sizeof(unsigned short);

    if (ws_size >= WS_NEEDED_E) {
        // PATH A: E-precompute (moves the 67 MB A-stream into a BW-bound prep pass)
        kAE_prep<<<783, 256, 0, stream>>>(seq, Bl, mem, Al, seq_bf, BnT, plusT, Ew, Zb, outp);
        k1b_phimu<<<512, 256, 0, stream>>>(BnT, mem, phimu);
        k23_fusedE<<<511, 256, 0, stream>>>(Ew, Zb, seq_bf, phimu, plusT, seq, outp);
    } else {
        // PATH B: round-0 proven kernels (145.6 us, absmax 0.0)
        kA_prep<<<272, 256, 0, stream>>>(seq, Bl, mem, seq_bf, BnT, plusT, outp);
        k1b_phimu<<<512, 256, 0, stream>>>(BnT, mem, phimu);
        k23_fused0<<<511, 256, 0, stream>>>(Al, seq_bf, phimu, plusT, seq, outp);
    }
}